// Round 16
// baseline (157.932 us; speedup 1.0000x reference)
//
#include <hip/hip_runtime.h>

// Bilateral filter, fixed shape: x[16,3,512,512] fp32, K=5, pad=2 reflect.
// sigma_color = sigma_space = 1.1; normalizations cancel in the ratio.
// w = exp2(coef2*(s+d^2)), coef2 = -log2(e)/2.42, s=(di-2)^2+(dj-2)^2.
//
// R11 (3rd submit -- prior two rounds were infra timeouts, never ran):
// R10's regression root-caused by counters: FETCH 106MB / WRITE 172MB
// (inputs+outputs are only 50MB each) + VALUBusy 71->42% = the Wn window
// spilled to SCRATCH. Cause: `const float* row = Wn[oi+di]` -- taking a
// pointer into the array blocked SROA (rule-20 variant). R6/R0 prove
// direct constant indexing keeps the window in VGPRs (48 VGPR, 49MB).
// Single change vs R10: delete the row pointer, index Wn[oi+di][dj+c]
// directly. Polynomial-weight structure unchanged and finally measured
// as intended:
//   w = Ws * P(d^2), P = deg-3 Chebyshev interpolant of exp2(coef2*u),
//   u=[0,1], rel err ~2e-5; Ws=exp2(coef2*s) folded per tap class at
//   compile time. Per px*tap: sub,mul,3fma,fma,add = 7 VALU = 14 cyc
//   (vs 18 w/ exp). Predict dispatch ~40-45us, FETCH/WRITE ~49MB,
//   VALUBusy ~70%+.
//
// One thread = 4x2 px tile; 6x8 f32 register window; center tap (w=1
// exact) folded into accumulator init. Plain scalar f32, no pointers
// into register arrays, no inline asm.
// Column reflect (verified R2-R4):
//   w0==0  : col -2 -> c4.z (col 2), col -1 -> l2.y (col 1)
//   w0==508: col 512 -> r2.x (col 510), col 513 -> c4.y (col 509)
// Row reflect: r = min(abs(r), 2*(H-1)-r).

constexpr int H_ = 512;
constexpr int W_ = 512;

// P(u) ~= exp2(coef2*u) on [0,1]; Chebyshev-node cubic interpolant.
// Audit: P(0)=0.999993, P(0.5)=0.813329 (true 0.813335), P(1)=0.661509
// (true 0.661510).
constexpr float PC0 = 0.999993f;
constexpr float PC1 = -0.412972f;
constexpr float PC2 = 0.0840929f;
constexpr float PC3 = -0.0096052f;

// WS[s] = exp2(coef2*s) = e^(-0.41322315*s) for s in {1,2,4,5,8}.
__device__ constexpr float WS_of(int s) {
    return s == 1 ? 0.6615123f
         : s == 2 ? 0.4376019f
         : s == 4 ? 0.1914962f
         : s == 5 ? 0.1266760f
         :          0.0366697f;   // s == 8
}

// One tap for one pixel: all array indices compile-time constants.
#define TAP(PIX, CEN, NUM, DEN)                                          \
    {                                                                    \
        float p = (PIX);                                                 \
        float d = p - (CEN);                                             \
        float u = d * d;                                                 \
        float w = __builtin_fmaf(                                        \
            __builtin_fmaf(__builtin_fmaf(K3, u, K2), u, K1), u, K0);    \
        NUM = __builtin_fmaf(w, p, NUM);                                 \
        DEN += w;                                                        \
    }

__global__ __launch_bounds__(256, 4) void bilateral_kernel(
    const float* __restrict__ x,
    float* __restrict__ out,
    int nthreads)
{
    int t = blockIdx.x * 256 + threadIdx.x;
    if (t >= nthreads) return;

    int qx = t & 127;          // tile col index (4-wide tiles)
    int rg = (t >> 7) & 255;   // tile row index (2-tall tiles)
    int pl = t >> 15;          // plane (b*C + c)
    int w0 = qx << 2;
    int h0 = rg << 1;
    const float* plane = x + ((long)pl << 18);   // 512*512
    float* oplane = out + ((long)pl << 18);

    int aL = max(w0 - 2, 0);
    int aR = min(w0 + 4, W_ - 2);
    bool bL = (w0 == 0);
    bool bR = (w0 == W_ - 4);

    // 6x8 window: rows h0-2..h0+3, cols w0-2..w0+5. Direct constant
    // indexing ONLY (no pointers into this array) -> stays in VGPRs.
    float Wn[6][8];
#pragma unroll
    for (int k = 0; k < 6; ++k) {
        int r = h0 + k - 2;
        r = min(abs(r), 2 * (H_ - 1) - r);
        const float* rp = plane + r * W_;
        float2 l2 = *(const float2*)(rp + aL);
        float4 c4 = *(const float4*)(rp + w0);
        float2 r2 = *(const float2*)(rp + aR);
        Wn[k][0] = bL ? c4.z : l2.x;   // reflect col -2 -> +2
        Wn[k][1] = l2.y;               // col -1 (== col 1 when bL)
        Wn[k][2] = c4.x; Wn[k][3] = c4.y; Wn[k][4] = c4.z; Wn[k][5] = c4.w;
        Wn[k][6] = r2.x;               // col +4 (== col 510 when bR)
        Wn[k][7] = bR ? c4.y : r2.y;   // reflect col 513 -> 509
    }

#pragma unroll
    for (int oi = 0; oi < 2; ++oi) {
        float c0 = Wn[oi + 2][2], c1 = Wn[oi + 2][3];
        float c2 = Wn[oi + 2][4], c3 = Wn[oi + 2][5];
        // Center tap folded exactly: w = 1.
        float num0 = c0, num1 = c1, num2 = c2, num3 = c3;
        float den0 = 1.f, den1 = 1.f, den2 = 1.f, den3 = 1.f;
#pragma unroll
        for (int di = 0; di < 5; ++di) {
#pragma unroll
            for (int dj = 0; dj < 5; ++dj) {
                if (di == 2 && dj == 2) continue;   // center handled above
                const int s = (di - 2) * (di - 2) + (dj - 2) * (dj - 2);
                const float K3 = WS_of(s) * PC3;    // compile-time folds
                const float K2 = WS_of(s) * PC2;
                const float K1 = WS_of(s) * PC1;
                const float K0 = WS_of(s) * PC0;
                TAP(Wn[oi + di][dj + 0], c0, num0, den0)
                TAP(Wn[oi + di][dj + 1], c1, num1, den1)
                TAP(Wn[oi + di][dj + 2], c2, num2, den2)
                TAP(Wn[oi + di][dj + 3], c3, num3, den3)
            }
        }
        float4 o;
        o.x = num0 * __builtin_amdgcn_rcpf(den0);
        o.y = num1 * __builtin_amdgcn_rcpf(den1);
        o.z = num2 * __builtin_amdgcn_rcpf(den2);
        o.w = num3 * __builtin_amdgcn_rcpf(den3);
        *(float4*)(oplane + (h0 + oi) * W_ + w0) = o;
    }
}

extern "C" void kernel_launch(void* const* d_in, const int* in_sizes, int n_in,
                              void* d_out, int out_size, void* d_ws, size_t ws_size,
                              hipStream_t stream)
{
    const float* x = (const float*)d_in[0];
    float* out = (float*)d_out;
    int nthreads = in_sizes[0] >> 3;         // 8 px per thread (4x2 tile)
    int blocks = (nthreads + 255) / 256;
    bilateral_kernel<<<blocks, 256, 0, stream>>>(x, out, nthreads);
}

// Round 17
// 148.082 us; speedup vs baseline: 1.0665x; 1.0665x over previous
//
#include <hip/hip_runtime.h>

// Bilateral filter, fixed shape: x[16,3,512,512] fp32, K=5, pad=2 reflect.
// sigma_color = sigma_space = 1.1; normalizations cancel in the ratio.
// w = exp2(coef2*(s+d^2)) = Ws * P(d^2); P = deg-3 Chebyshev interp of
// exp2(coef2*u) on u=[0,1] (rel err ~1e-5); Ws folded per tap class.
//
// R12: R11 DISPROVED the row-pointer theory -- traffic identical to R10
// (FETCH 106MB/WRITE 172MB, VGPR 64, 95us). Spill arithmetic: ~20 values
// spilled/thread; VGPR stopped EXACTLY at 64 = the 8-waves/SIMD occupancy
// tier, while live set is ~70. Diagnosis: allocator chases 8 waves/EU
// (launch_bounds min-waves only sets a floor) and spills the overhang.
// R11 also VERIFIED the polynomial numerics on-device (absmax 0.0039 =
// floor). This round removes the spill two ways at once:
//   1. amdgpu_waves_per_eu(4,4): max=4 kills the 8-wave incentive;
//      VGPR budget 128 >> ~70 needed.
//   2. window as 48 NAMED SCALARS (w00..w57, macro taps) -- no array,
//      no SROA/localMem question at all.
// Predict: FETCH/WRITE -> ~49MB each, VGPR 70-100, VALUBusy >=70%,
// dispatch ~42-46us (2900 cyc/wave vs R6 3650 @ 53.8us).
//
// One thread = 4x2 px tile; 6x8 named-scalar window; center tap (w=1
// exact) folded into accumulator init. Plain scalar f32, no inline asm.
// Column reflect (verified R2-R4):
//   w0==0  : col -2 -> cv.z (col 2), col -1 -> lv.y (col 1)
//   w0==508: col 512 -> rv.x (col 510), col 513 -> cv.y (col 509)
// Row reflect: r = min(abs(r), 2*(H-1)-r).

constexpr int H_ = 512;
constexpr int W_ = 512;

// P(u) ~= exp2(coef2*u), coef2 = -log2(e)/2.42. Audit: P(0)=0.999993,
// P(0.5)=0.813330 (true 0.813335), P(1)=0.661509 (true 0.661512).
constexpr float PC0 = 0.999993f;
constexpr float PC1 = -0.412972f;
constexpr float PC2 = 0.0840929f;
constexpr float PC3 = -0.0096052f;

// Per-class coefficients K*_s = exp2(coef2*s) * PC*, s=(di-2)^2+(dj-2)^2.
#define DEFK(S, WS)                              \
    constexpr float K0_##S = (WS) * PC0;         \
    constexpr float K1_##S = (WS) * PC1;         \
    constexpr float K2_##S = (WS) * PC2;         \
    constexpr float K3_##S = (WS) * PC3;
DEFK(1, 0.6615123f)   // e^-0.413223
DEFK(2, 0.4376019f)   // ^2
DEFK(4, 0.1914962f)   // ^4
DEFK(5, 0.1266760f)   // ^5
DEFK(8, 0.0366697f)   // ^8

// One tap: w = P_s(d^2) (class-folded), accumulate num/den.
#define TAP(P, C, N, D, S)                                               \
    {                                                                    \
        float d_ = (P) - (C);                                            \
        float u_ = d_ * d_;                                              \
        float wt_ = __builtin_fmaf(                                      \
            __builtin_fmaf(__builtin_fmaf(K3_##S, u_, K2_##S), u_,       \
                           K1_##S), u_, K0_##S);                         \
        N = __builtin_fmaf(wt_, (P), N);                                 \
        D += wt_;                                                        \
    }

// 4 pixels (centers cen0..cen3) tap columns C0..C3 of row R, class S.
#define TAP4(R, C0, C1, C2, C3, S)           \
    TAP(w##R##C0, cen0, num0, den0, S)       \
    TAP(w##R##C1, cen1, num1, den1, S)       \
    TAP(w##R##C2, cen2, num2, den2, S)       \
    TAP(w##R##C3, cen3, num3, den3, S)

// Full row of 5 dj-blocks (classes SA..SE), and center-row variant
// (dj=2 block == the 4 center self-taps, folded into accum init).
#define ROW5(R, SA, SB, SC, SD, SE) \
    TAP4(R, 0, 1, 2, 3, SA)         \
    TAP4(R, 1, 2, 3, 4, SB)         \
    TAP4(R, 2, 3, 4, 5, SC)         \
    TAP4(R, 3, 4, 5, 6, SD)         \
    TAP4(R, 4, 5, 6, 7, SE)
#define ROW5_CEN(R, SA, SB, SD, SE) \
    TAP4(R, 0, 1, 2, 3, SA)         \
    TAP4(R, 1, 2, 3, 4, SB)         \
    TAP4(R, 3, 4, 5, 6, SD)         \
    TAP4(R, 4, 5, 6, 7, SE)

// Load one padded row (reflect) into 8 named scalars.
#define LOADROW(R, RIDX)                              \
    {                                                 \
        int r_ = (RIDX);                              \
        r_ = min(abs(r_), 2 * (H_ - 1) - r_);         \
        const float* rp_ = plane + r_ * W_;           \
        float2 lv = *(const float2*)(rp_ + aL);       \
        float4 cv = *(const float4*)(rp_ + w0);       \
        float2 rv = *(const float2*)(rp_ + aR);       \
        w##R##0 = bL ? cv.z : lv.x;                   \
        w##R##1 = lv.y;                               \
        w##R##2 = cv.x; w##R##3 = cv.y;               \
        w##R##4 = cv.z; w##R##5 = cv.w;               \
        w##R##6 = rv.x;                               \
        w##R##7 = bR ? cv.y : rv.y;                   \
    }

__global__ void
__attribute__((amdgpu_flat_work_group_size(256, 256),
               amdgpu_waves_per_eu(4, 4)))
bilateral_kernel(const float* __restrict__ x,
                 float* __restrict__ out,
                 int nthreads)
{
    int t = blockIdx.x * 256 + threadIdx.x;
    if (t >= nthreads) return;

    int qx = t & 127;          // tile col index (4-wide tiles)
    int rg = (t >> 7) & 255;   // tile row index (2-tall tiles)
    int pl = t >> 15;          // plane (b*C + c)
    int w0 = qx << 2;
    int h0 = rg << 1;
    const float* plane = x + ((long)pl << 18);   // 512*512
    float* oplane = out + ((long)pl << 18);

    int aL = max(w0 - 2, 0);
    int aR = min(w0 + 4, W_ - 2);
    bool bL = (w0 == 0);
    bool bR = (w0 == W_ - 4);

    // 6x8 window as named scalars: rows 0..5 = h0-2..h0+3, cols 0..7 =
    // w0-2..w0+5. No arrays -> register residency by construction.
    float w00, w01, w02, w03, w04, w05, w06, w07;
    float w10, w11, w12, w13, w14, w15, w16, w17;
    float w20, w21, w22, w23, w24, w25, w26, w27;
    float w30, w31, w32, w33, w34, w35, w36, w37;
    float w40, w41, w42, w43, w44, w45, w46, w47;
    float w50, w51, w52, w53, w54, w55, w56, w57;
    LOADROW(0, h0 - 2)
    LOADROW(1, h0 - 1)
    LOADROW(2, h0 + 0)
    LOADROW(3, h0 + 1)
    LOADROW(4, h0 + 2)
    LOADROW(5, h0 + 3)

    // ---- output row h0 (window rows 0..4, centers w22..w25) ----
    {
        float cen0 = w22, cen1 = w23, cen2 = w24, cen3 = w25;
        float num0 = cen0, num1 = cen1, num2 = cen2, num3 = cen3;
        float den0 = 1.f, den1 = 1.f, den2 = 1.f, den3 = 1.f;
        ROW5(0, 8, 5, 4, 5, 8)        // di=0: s = 4+{4,1,0,1,4}
        ROW5(1, 5, 2, 1, 2, 5)        // di=1: s = 1+{...}
        ROW5_CEN(2, 4, 1, 1, 4)       // di=2: s = 0+{...}, dj=2 folded
        ROW5(3, 5, 2, 1, 2, 5)
        ROW5(4, 8, 5, 4, 5, 8)
        float4 o;
        o.x = num0 * __builtin_amdgcn_rcpf(den0);
        o.y = num1 * __builtin_amdgcn_rcpf(den1);
        o.z = num2 * __builtin_amdgcn_rcpf(den2);
        o.w = num3 * __builtin_amdgcn_rcpf(den3);
        *(float4*)(oplane + h0 * W_ + w0) = o;
    }

    // ---- output row h0+1 (window rows 1..5, centers w32..w35) ----
    {
        float cen0 = w32, cen1 = w33, cen2 = w34, cen3 = w35;
        float num0 = cen0, num1 = cen1, num2 = cen2, num3 = cen3;
        float den0 = 1.f, den1 = 1.f, den2 = 1.f, den3 = 1.f;
        ROW5(1, 8, 5, 4, 5, 8)
        ROW5(2, 5, 2, 1, 2, 5)
        ROW5_CEN(3, 4, 1, 1, 4)
        ROW5(4, 5, 2, 1, 2, 5)
        ROW5(5, 8, 5, 4, 5, 8)
        float4 o;
        o.x = num0 * __builtin_amdgcn_rcpf(den0);
        o.y = num1 * __builtin_amdgcn_rcpf(den1);
        o.z = num2 * __builtin_amdgcn_rcpf(den2);
        o.w = num3 * __builtin_amdgcn_rcpf(den3);
        *(float4*)(oplane + (h0 + 1) * W_ + w0) = o;
    }
}

extern "C" void kernel_launch(void* const* d_in, const int* in_sizes, int n_in,
                              void* d_out, int out_size, void* d_ws, size_t ws_size,
                              hipStream_t stream)
{
    const float* x = (const float*)d_in[0];
    float* out = (float*)d_out;
    int nthreads = in_sizes[0] >> 3;         // 8 px per thread (4x2 tile)
    int blocks = (nthreads + 255) / 256;
    bilateral_kernel<<<blocks, 256, 0, stream>>>(x, out, nthreads);
}